// Round 3
// baseline (3110.884 us; speedup 1.0000x reference)
//
#include <hip/hip_runtime.h>
#include <math.h>

#define NTH 256

// float4 index of S cell (row i, col-chunk m): rotate-by-chunk swizzle.
__device__ __forceinline__ int SC4(int i, int m) { return m * 64 + ((i + m) & 63); }

// broadcast lane `ln`'s value of v to all lanes (uniform ln required!)
__device__ __forceinline__ float rl(float v, int ln) {
  return __int_as_float(__builtin_amdgcn_readlane(__float_as_int(v), ln));
}

// acc = sum_k As[t*64+k] * v[k]; both reads b128 with per-lane chunk rotation
// so 64 lanes cover all 8 bank-quads per instruction (row stride 256B trap).
__device__ __forceinline__ float dot64_row(const float4* __restrict__ As4,
                                           const float4* __restrict__ v4, int t) {
  float acc = 0.f;
#pragma unroll
  for (int q = 0; q < 16; ++q) {
    int qq = (q + t) & 15;
    float4 a = As4[t * 16 + qq];
    float4 b = v4[qq];
    acc = fmaf(a.x, b.x, acc); acc = fmaf(a.y, b.y, acc);
    acc = fmaf(a.z, b.z, acc); acc = fmaf(a.w, b.w, acc);
  }
  return acc;
}

// S = A * diag(w) * A^T, symmetric: 136 upper 4x4 tiles + mirrored writes.
__device__ __forceinline__ void form_S_sym(const float4* __restrict__ As4,
                                           const float4* __restrict__ wv4,
                                           float4* __restrict__ Sb4,
                                           int bi, int bj, bool act) {
  if (!act) return;
  float a00=0,a01=0,a02=0,a03=0,a10=0,a11=0,a12=0,a13=0;
  float a20=0,a21=0,a22=0,a23=0,a30=0,a31=0,a32=0,a33=0;
  for (int c4 = 0; c4 < 64; ++c4) {
    float4 w4 = wv4[c4];
#pragma unroll
    for (int e = 0; e < 4; ++e) {
      float wc = (e==0)?w4.x:(e==1)?w4.y:(e==2)?w4.z:w4.w;
      int c = 4*c4 + e;
      float4 a4 = As4[c*16 + bi];   // broadcast-ish across same-bi lanes
      float4 b4 = As4[c*16 + bj];   // 16 distinct float4 -> ~2-way, free
      float bx = b4.x*wc, by = b4.y*wc, bz = b4.z*wc, bw = b4.w*wc;
      a00=fmaf(a4.x,bx,a00); a01=fmaf(a4.x,by,a01); a02=fmaf(a4.x,bz,a02); a03=fmaf(a4.x,bw,a03);
      a10=fmaf(a4.y,bx,a10); a11=fmaf(a4.y,by,a11); a12=fmaf(a4.y,bz,a12); a13=fmaf(a4.y,bw,a13);
      a20=fmaf(a4.z,bx,a20); a21=fmaf(a4.z,by,a21); a22=fmaf(a4.z,bz,a22); a23=fmaf(a4.z,bw,a23);
      a30=fmaf(a4.w,bx,a30); a31=fmaf(a4.w,by,a31); a32=fmaf(a4.w,bz,a32); a33=fmaf(a4.w,bw,a33);
    }
  }
  Sb4[SC4(4*bi+0,bj)] = make_float4(a00,a01,a02,a03);
  Sb4[SC4(4*bi+1,bj)] = make_float4(a10,a11,a12,a13);
  Sb4[SC4(4*bi+2,bj)] = make_float4(a20,a21,a22,a23);
  Sb4[SC4(4*bi+3,bj)] = make_float4(a30,a31,a32,a33);
  if (bi != bj) {                    // mirror (transposed) tile
    Sb4[SC4(4*bj+0,bi)] = make_float4(a00,a10,a20,a30);
    Sb4[SC4(4*bj+1,bi)] = make_float4(a01,a11,a21,a31);
    Sb4[SC4(4*bj+2,bi)] = make_float4(a02,a12,a22,a32);
    Sb4[SC4(4*bj+3,bi)] = make_float4(a03,a13,a23,a33);
  }
}

// lane i holds row i of S in r[64]; in-place Gauss-Jordan inverse (SPD, no pivot).
// Fully unrolled: readlane lane-index must be compile-time-uniform, r[] static-indexed.
__device__ __forceinline__ void gj64(float (&r)[64], int lane) {
#pragma unroll
  for (int j = 0; j < 64; ++j) {
    float p = rl(r[j], j);          // pivot S[j][j]
    float invp = 1.0f / p;
    float ci = r[j];                // my column-j entry
    float cis = (lane == j) ? (1.0f - invp) : ci * invp;
#pragma unroll
    for (int k = 0; k < 64; ++k) {
      if (k == j) continue;
      r[k] = fmaf(-cis, rl(r[k], j), r[k]);   // readlane = pre-update row j
    }
    r[j] = (lane == j) ? invp : (-ci * invp);
  }
}

__device__ __forceinline__ void loadS(float (&r)[64], const float* __restrict__ Sb, int lane) {
  const float4* Sb4 = (const float4*)Sb;
#pragma unroll
  for (int m = 0; m < 16; ++m) {
    float4 v = Sb4[SC4(lane, m)];
    r[4*m+0]=v.x; r[4*m+1]=v.y; r[4*m+2]=v.z; r[4*m+3]=v.w;
  }
}

// out_lane = sum_j Sinv[lane][j] * rh[j]   (rh distributed one value per lane)
__device__ __forceinline__ float matS64(const float (&r)[64], float rh) {
  float acc = 0.f;
#pragma unroll
  for (int j = 0; j < 64; ++j) acc = fmaf(r[j], rl(rh, j), acc);
  return acc;
}

__global__ __launch_bounds__(NTH)
void optnet_kernel(const float* __restrict__ x,  const float* __restrict__ W1,
                   const float* __restrict__ b1, const float* __restrict__ W2,
                   const float* __restrict__ b2, const float* __restrict__ A,
                   float* __restrict__ out)
{
  extern __shared__ float sm[];
  const int b = blockIdx.x;
  const int t = threadIdx.x;
  const int lane = t & 63;
  const int wav = t >> 6;

  float* As    = sm;               // 16384: A^T c-major, As[c*64+k] = A[k][c]
  float* Sb    = sm + 16384;       // 4096:  S (swizzled chunk-major)
  float* xld   = Sb;               // alias (first 1024) during h-compute
  float* h     = sm + 20480;       // 256
  float* z     = h + 256;          // 256
  float* wHd   = z + 256;          // 256: 1/Hd
  float* wtp   = wHd + 256;        // 256: top/Hd
  float* partA = wtp + 256;        // 256: re partials / logits partials
  float* partB = partA + 256;      // 256: A@wtp partials
  float* nu    = partB + 256;      // 64
  float* rev   = nu + 64;          // 64
  float* dnu   = rev + 64;         // 64
  float* red   = dnu + 64;         // 16

  const float4* As4  = (const float4*)As;
  float4*       Sb4  = (float4*)Sb;
  const float4* wv4  = (const float4*)wHd;
  const float4* nu4  = (const float4*)nu;
  const float4* dnu4 = (const float4*)dnu;

  // upper-triangular 4x4 tile map for form_S (t < 136)
  int bi = 0, bj = 0;
  if (t < 136) {
    int rr = t;
    while (rr >= 16 - bi) { rr -= 16 - bi; ++bi; }
    bj = bi + rr;
  }
  const bool sact = (t < 136);

  // ---- stage A^T (c-major) and x row ----
  for (int g = t; g < 64 * 256; g += NTH)
    As[(g & 255) * 64 + (g >> 8)] = A[g];
  for (int g = t; g < 1024; g += NTH)
    xld[g] = x[b * 1024 + g];
  __syncthreads();

  // ---- h = relu(x @ W1^T + b1) ----
  {
    const float4* xr = (const float4*)xld;
    for (int jj = 0; jj < 64; ++jj) {
      int j = (wav << 6) + jj;
      const float4* w1r = (const float4*)(W1 + (size_t)j * 1024);
      float acc = 0.f;
#pragma unroll
      for (int mm = 0; mm < 4; ++mm) {
        float4 a = w1r[lane + (mm << 6)];
        float4 xv = xr[lane + (mm << 6)];
        acc = fmaf(a.x,xv.x,fmaf(a.y,xv.y,fmaf(a.z,xv.z,fmaf(a.w,xv.w,acc))));
      }
#pragma unroll
      for (int off = 32; off > 0; off >>= 1) acc += __shfl_xor(acc, off, 64);
      if (lane == 0) { float v = acc + b1[j]; h[j] = v > 0.f ? v : 0.f; }
    }
  }
  __syncthreads();
  const float hr = h[t];

  float r[64];                      // wave0: S / Sinv row (register-resident)

  // ---- initial solve: Hd = QPEN -> S0 = 10*A*A^T ----
  wHd[t] = 10.0f;
  wtp[t] = hr * 10.0f;
  __syncthreads();
  form_S_sym(As4, wv4, Sb4, bi, bj, sact);
  __syncthreads();
  if (wav == 0) {
    loadS(r, Sb, lane);
    gj64(r, lane);
  } else {                          // overlap: A @ (h/QPEN) partials
    int lo = (wav - 1) * 86, hi = lo + 86; if (hi > 256) hi = 256;
    float accB = 0.f;
    for (int c = lo; c < hi; ++c)
      accB = fmaf(wtp[c], As[c * 64 + lane], accB);
    partB[(wav << 6) + lane] = accB;
  }
  __syncthreads();
  if (t < 64) {
    float rh = partB[64 + t] + partB[128 + t] + partB[192 + t] - 1.0f;
    nu[t] = matS64(r, rh);
  }
  __syncthreads();

  float zt, st, lt;
  {
    float atd = dot64_row(As4, nu4, t);   // (A^T nu)_t
    zt = (hr - atd) * 10.0f;
    z[t] = zt;
    st = fmaxf(zt, 1.0f);
    lt = 1.0f;
  }
  __syncthreads();

  // ---- 12 predictor-corrector IP iterations ----
  for (int it = 0; it < 12; ++it) {
    const float nuA = dot64_row(As4, nu4, t);      // (nu @ A)_t
    const float rxt = 0.1f * zt - hr - lt + nuA;   // p = -h
    const float rit = st - zt;
    const float Dt  = lt / st;
    const float wt  = 1.0f / (0.1f + Dt);
    const float rs1 = lt * st;
    const float g1  = (lt * rit - rs1) / st;
    const float top1 = -rxt + g1;                  // pre-GJ: enables overlap
    wHd[t] = wt;
    wtp[t] = top1 * wt;
    __syncthreads();                               // wHd, wtp ready
    form_S_sym(As4, wv4, Sb4, bi, bj, sact);
    __syncthreads();                               // S ready
    if (wav == 0) {
      loadS(r, Sb, lane);
      gj64(r, lane);                               // ~17K cy VALU, no LDS/barriers
    } else {                                       // hidden under GJ
      int lo = (wav - 1) * 86, hi = lo + 86; if (hi > 256) hi = 256;
      float accA = 0.f, accB = 0.f;
      for (int c = lo; c < hi; ++c) {
        float av = As[c * 64 + lane];
        accA = fmaf(z[c],   av, accA);             // re partial
        accB = fmaf(wtp[c], av, accB);             // A@wtp partial
      }
      partA[(wav << 6) + lane] = accA;
      partB[(wav << 6) + lane] = accB;
    }
    __syncthreads();                               // Sinv in regs; partials ready
    if (t < 64) {
      float re_t = partA[64 + t] + partA[128 + t] + partA[192 + t] - 1.0f;
      rev[t] = re_t;
      float rh = partB[64 + t] + partB[128 + t] + partB[192 + t] + re_t;
      dnu[t] = matS64(r, rh);
    }
    __syncthreads();                               // dnu, rev ready
    float dza, dsa, dla;
    {
      float atd = dot64_row(As4, dnu4, t);
      dza = (top1 - atd) * wt;
      dsa = dza - rit;
      dla = g1 - Dt * dza;
    }
    {
      float r1 = dsa < 0.f ? -st / dsa : 1e10f;
      float r2 = dla < 0.f ? -lt / dla : 1e10f;
      float mn = fminf(r1, r2);
#pragma unroll
      for (int off = 32; off > 0; off >>= 1) mn = fminf(mn, __shfl_xor(mn, off, 64));
      if (lane == 0) red[wav] = mn;
    }
    __syncthreads();
    const float a_aff = fminf(1.0f, 0.999f * fminf(fminf(red[0],red[1]), fminf(red[2],red[3])));
    {
      float p1 = st * lt;
      float p2 = (st + a_aff * dsa) * (lt + a_aff * dla);
#pragma unroll
      for (int off = 32; off > 0; off >>= 1) { p1 += __shfl_xor(p1,off,64); p2 += __shfl_xor(p2,off,64); }
      if (lane == 0) { red[4 + wav] = p1; red[8 + wav] = p2; }
    }
    __syncthreads();
    const float mu  = (red[4] + red[5] + red[6]  + red[7])  * (1.0f / 256.0f);
    const float mua = (red[8] + red[9] + red[10] + red[11]) * (1.0f / 256.0f);
    float sig = mua / mu; sig = sig * sig * sig;
    const float smu = sig * mu;
    const float rs2 = lt * st + dsa * dla - smu;
    const float g2  = (lt * rit - rs2) / st;
    const float top2 = -rxt + g2;
    wtp[t] = top2 * wt;
    __syncthreads();                               // wtp2 ready
    {
      float accB = 0.f;
      for (int cc = 0; cc < 64; ++cc) {
        int c = (wav << 6) + cc;
        accB = fmaf(wtp[c], As[c * 64 + lane], accB);
      }
      partB[t] = accB;
    }
    __syncthreads();
    if (t < 64) {
      float rh = partB[t] + partB[64 + t] + partB[128 + t] + partB[192 + t] + rev[t];
      dnu[t] = matS64(r, rh);
    }
    __syncthreads();
    float dz2, ds2, dl2;
    {
      float atd = dot64_row(As4, dnu4, t);
      dz2 = (top2 - atd) * wt;
      ds2 = dz2 - rit;
      dl2 = g2 - Dt * dz2;
    }
    {
      float r1 = ds2 < 0.f ? -st / ds2 : 1e10f;
      float r2 = dl2 < 0.f ? -lt / dl2 : 1e10f;
      float mn = fminf(r1, r2);
#pragma unroll
      for (int off = 32; off > 0; off >>= 1) mn = fminf(mn, __shfl_xor(mn, off, 64));
      if (lane == 0) red[wav] = mn;
    }
    __syncthreads();
    const float a = fminf(1.0f, 0.999f * fminf(fminf(red[0],red[1]), fminf(red[2],red[3])));
    zt += a * dz2;
    st = fmaxf(st + a * ds2, 1e-8f);
    lt = fmaxf(lt + a * dl2, 1e-8f);
    z[t] = zt;
    if (t < 64) nu[t] += a * dnu[t];
    __syncthreads();
  }

  // ---- logits = z @ W2^T + b2 ; log_softmax ----
  if (t < 160) {
    int cls = t >> 4, pp = t & 15;
    float acc = 0.f;
#pragma unroll
    for (int e = 0; e < 16; ++e) {
      int c = (pp << 4) + e;
      acc = fmaf(z[c], W2[cls * 256 + c], acc);
    }
    partA[t] = acc;
  }
  __syncthreads();
  if (t < 10) {
    float s = b2[t];
#pragma unroll
    for (int pp = 0; pp < 16; ++pp) s += partA[(t << 4) + pp];
    red[t] = s;
  }
  __syncthreads();
  if (t == 0) {
    float mx = red[0];
#pragma unroll
    for (int c = 1; c < 10; ++c) mx = fmaxf(mx, red[c]);
    float se = 0.f;
#pragma unroll
    for (int c = 0; c < 10; ++c) se += expf(red[c] - mx);
    float lse = mx + logf(se);
    for (int c = 0; c < 10; ++c) out[b * 10 + c] = red[c] - lse;
  }
}

extern "C" void kernel_launch(void* const* d_in, const int* in_sizes, int n_in,
                              void* d_out, int out_size, void* d_ws, size_t ws_size,
                              hipStream_t stream) {
  (void)in_sizes; (void)n_in; (void)out_size; (void)d_ws; (void)ws_size;
  const float* x  = (const float*)d_in[0];
  const float* W1 = (const float*)d_in[1];
  const float* b1 = (const float*)d_in[2];
  const float* W2 = (const float*)d_in[3];
  const float* b2 = (const float*)d_in[4];
  const float* A  = (const float*)d_in[5];
  float* out = (float*)d_out;

  const size_t shmem = (16384 + 4096 + 6 * 256 + 3 * 64 + 16) * sizeof(float); // 88896 B
  (void)hipFuncSetAttribute((const void*)optnet_kernel,
                            hipFuncAttributeMaxDynamicSharedMemorySize, (int)shmem);
  optnet_kernel<<<128, NTH, shmem, stream>>>(x, W1, b1, W2, b2, A, out);
}